// Round 10
// baseline (163.221 us; speedup 1.0000x reference)
//
#include <hip/hip_runtime.h>

// Problem constants (fixed by setup_inputs: (2, 64, 320, 320), stoken 16x16)
#define KB   2
#define KC   64
#define KH   320
#define KW   320
#define KSH  16
#define KSW  16
#define KNSH 20
#define KNSW 20
#define KNS  400           // KNSH*KNSW
#define KN   102400        // KH*KW

typedef float float4v __attribute__((ext_vector_type(4)));

// ---------------------------------------------------------------------------
// Kernel A: spix0 = per-block mean of pixel features.
__global__ __launch_bounds__(320) void block_mean_kernel(
    const float* __restrict__ pf, float* __restrict__ spix) {
  int wg = blockIdx.x;
  int rb = wg % KNSH;
  int c  = (wg / KNSH) % KC;
  int b  = wg / (KNSH * KC);
  int t  = threadIdx.x;  // 0..319

  const float* row0 = pf + ((size_t)(b * KC + c) * KH + rb * KSH) * KW;
  float acc = 0.f;
#pragma unroll
  for (int i = 0; i < KSH; ++i) acc += row0[i * KW + t];

#pragma unroll
  for (int off = 8; off > 0; off >>= 1) acc += __shfl_down(acc, off, 16);

  if ((t & 15) == 0)
    spix[(b * KC + c) * KNS + rb * KNSW + (t >> 4)] = acc * (1.0f / (KSH * KSW));
}

// ---------------------------------------------------------------------------
// Kernel BS: FUSED iter-0 dist/softmax + scatter-partials (R8-proven).
// part[((b*KNS+blk)*9 + k)*64 + c] = sum_{p in blk} aff0_k[p] * pf_c[p]
// den[(b*KNS+blk)*9 + k]           = sum_{p in blk} aff0_k[p]
__global__ __launch_bounds__(256) void dist_partial_kernel(
    const float* __restrict__ pf, const float* __restrict__ spix,
    float* __restrict__ part, float* __restrict__ den) {
  __shared__ float scand[9][KC];
  __shared__ __align__(16) float aff_s[9][256];
  __shared__ float part_s[9][64];
  __shared__ float den_s[9];

  int wg = blockIdx.x;
  int s  = wg % KNS;
  int b  = wg / KNS;
  int sr = s / KNSW, sc = s % KNSW;
  int t  = threadIdx.x;

  // stage the 9 candidate centroids
  for (int idx = t; idx < 9 * KC; idx += 256) {
    int k = idx >> 6, c = idx & 63;
    int rr = sr + k / 3 - 1, cc = sc + k % 3 - 1;
    float v = 0.f;
    if (rr >= 0 && rr < KNSH && cc >= 0 && cc < KNSW)
      v = spix[(b * KC + c) * KNS + rr * KNSW + cc];
    scand[k][c] = v;
  }
  __syncthreads();

  // --- B phase: per-pixel distances + masked softmax (thread t = pixel t) ---
  int ti = t >> 4, tj = t & 15;
  int p = (sr * KSH + ti) * KW + sc * KSW + tj;
  const float* pfp = pf + (size_t)b * KC * KN + p;

  float d[9];
#pragma unroll
  for (int k = 0; k < 9; ++k) d[k] = 0.f;
  for (int c = 0; c < KC; ++c) {
    float x = pfp[(size_t)c * KN];
#pragma unroll
    for (int k = 0; k < 9; ++k) {
      float df = x - scand[k][c];
      d[k] = fmaf(df, df, d[k]);
    }
  }
  float m = 3.4e38f;
#pragma unroll
  for (int k = 0; k < 9; ++k) {
    int rr = sr + k / 3 - 1, cc = sc + k % 3 - 1;
    if (rr >= 0 && rr < KNSH && cc >= 0 && cc < KNSW) m = fminf(m, d[k]);
  }
  float e[9];
  float sum = 0.f;
#pragma unroll
  for (int k = 0; k < 9; ++k) {
    int rr = sr + k / 3 - 1, cc = sc + k % 3 - 1;
    bool valid = (rr >= 0 && rr < KNSH && cc >= 0 && cc < KNSW);
    e[k] = valid ? __expf(m - d[k]) : 0.f;
    sum += e[k];
  }
  float inv = 1.0f / sum;
#pragma unroll
  for (int k = 0; k < 9; ++k) aff_s[k][t] = e[k] * inv;
  __syncthreads();

  // --- S1 phase: scatter partials ---
  int w = t >> 6, l = t & 63;
  int li = l >> 2, lj4 = (l & 3) * 4;
  const float* pfb = pf + ((size_t)b * KC + w * 16) * KN
                   + (sr * KSH + li) * KW + sc * KSW + lj4;

  const float4v a0 = *(const float4v*)(&aff_s[0][l * 4]);
  const float4v a1 = *(const float4v*)(&aff_s[1][l * 4]);
  const float4v a2 = *(const float4v*)(&aff_s[2][l * 4]);
  const float4v a3 = *(const float4v*)(&aff_s[3][l * 4]);
  const float4v a4 = *(const float4v*)(&aff_s[4][l * 4]);
  const float4v a5 = *(const float4v*)(&aff_s[5][l * 4]);
  const float4v a6 = *(const float4v*)(&aff_s[6][l * 4]);
  const float4v a7 = *(const float4v*)(&aff_s[7][l * 4]);
  const float4v a8 = *(const float4v*)(&aff_s[8][l * 4]);

  if (w == 0) {
#define DENK(k, av)                                                       \
    {                                                                     \
      float dv = (av.x + av.y) + (av.z + av.w);                           \
      _Pragma("unroll")                                                   \
      for (int off = 32; off > 0; off >>= 1) dv += __shfl_xor(dv, off, 64); \
      if (l == 0) den_s[k] = dv;                                          \
    }
    DENK(0, a0) DENK(1, a1) DENK(2, a2) DENK(3, a3) DENK(4, a4)
    DENK(5, a5) DENK(6, a6) DENK(7, a7) DENK(8, a8)
#undef DENK
  }

#pragma unroll
  for (int cb = 0; cb < 4; ++cb) {
    float4v x0 = *(const float4v*)(pfb + (size_t)(cb * 4 + 0) * KN);
    float4v x1 = *(const float4v*)(pfb + (size_t)(cb * 4 + 1) * KN);
    float4v x2 = *(const float4v*)(pfb + (size_t)(cb * 4 + 2) * KN);
    float4v x3 = *(const float4v*)(pfb + (size_t)(cb * 4 + 3) * KN);

    float acc[4][9];
#define DOTS(c, xv)                                                        \
    acc[c][0] = fmaf(xv.x, a0.x, fmaf(xv.y, a0.y, fmaf(xv.z, a0.z, xv.w * a0.w))); \
    acc[c][1] = fmaf(xv.x, a1.x, fmaf(xv.y, a1.y, fmaf(xv.z, a1.z, xv.w * a1.w))); \
    acc[c][2] = fmaf(xv.x, a2.x, fmaf(xv.y, a2.y, fmaf(xv.z, a2.z, xv.w * a2.w))); \
    acc[c][3] = fmaf(xv.x, a3.x, fmaf(xv.y, a3.y, fmaf(xv.z, a3.z, xv.w * a3.w))); \
    acc[c][4] = fmaf(xv.x, a4.x, fmaf(xv.y, a4.y, fmaf(xv.z, a4.z, xv.w * a4.w))); \
    acc[c][5] = fmaf(xv.x, a5.x, fmaf(xv.y, a5.y, fmaf(xv.z, a5.z, xv.w * a5.w))); \
    acc[c][6] = fmaf(xv.x, a6.x, fmaf(xv.y, a6.y, fmaf(xv.z, a6.z, xv.w * a6.w))); \
    acc[c][7] = fmaf(xv.x, a7.x, fmaf(xv.y, a7.y, fmaf(xv.z, a7.z, xv.w * a7.w))); \
    acc[c][8] = fmaf(xv.x, a8.x, fmaf(xv.y, a8.y, fmaf(xv.z, a8.z, xv.w * a8.w)));
    DOTS(0, x0) DOTS(1, x1) DOTS(2, x2) DOTS(3, x3)
#undef DOTS

#pragma unroll
    for (int off = 32; off > 0; off >>= 1)
#pragma unroll
      for (int c = 0; c < 4; ++c)
#pragma unroll
        for (int k = 0; k < 9; ++k)
          acc[c][k] += __shfl_xor(acc[c][k], off, 64);

    if (l == 0) {
#pragma unroll
      for (int c = 0; c < 4; ++c)
#pragma unroll
        for (int k = 0; k < 9; ++k)
          part_s[k][w * 16 + cb * 4 + c] = acc[c][k];
    }
  }
  __syncthreads();

  size_t base = ((size_t)b * KNS + s) * 9;
  for (int idx = t; idx < 9 * 64; idx += 256)
    part[base * 64 + idx] = part_s[idx >> 6][idx & 63];
  if (t < 9) den[base + t] = den_s[t];
}

// ---------------------------------------------------------------------------
// Kernel B': iter-1 dist/softmax with S2 INLINED — candidate centroids are
// reduced directly from part/den (L2-resident, coalesced 64-float rows).
__global__ __launch_bounds__(256) void dist_aff2_kernel(
    const float* __restrict__ pf, const float* __restrict__ part,
    const float* __restrict__ den, float* __restrict__ aff) {
  __shared__ float scand[9][KC];

  int wg = blockIdx.x;
  int s  = wg % KNS;
  int b  = wg / KNS;
  int sr = s / KNSW, sc = s % KNSW;
  int t  = threadIdx.x;

  // scand[k][c] = spix1 of neighbor k, from the 9 partials around it
  for (int idx = t; idx < 9 * KC; idx += 256) {
    int k = idx >> 6, c = idx & 63;   // k uniform per 64-thread group
    int nr = sr + k / 3 - 1, nc = sc + k % 3 - 1;
    float v = 0.f;
    if (nr >= 0 && nr < KNSH && nc >= 0 && nc < KNSW) {
      float num = 0.f, dsum = 0.f;
#pragma unroll
      for (int j = 0; j < 9; ++j) {
        int rr = nr + j / 3 - 1, cc = nc + j % 3 - 1;
        if (rr >= 0 && rr < KNSH && cc >= 0 && cc < KNSW) {
          size_t base = ((size_t)b * KNS + rr * KNSW + cc) * 9 + (8 - j);
          num  += part[base * 64 + c];
          dsum += den[base];
        }
      }
      v = num / (dsum + 1e-16f);
    }
    scand[k][c] = v;
  }
  __syncthreads();

  int i = t >> 4, j = t & 15;
  int p = (sr * KSH + i) * KW + sc * KSW + j;
  const float* pfb = pf + (size_t)b * KC * KN + p;

  float d[9];
#pragma unroll
  for (int k = 0; k < 9; ++k) d[k] = 0.f;

  for (int c = 0; c < KC; ++c) {
    float x = pfb[(size_t)c * KN];
#pragma unroll
    for (int k = 0; k < 9; ++k) {
      float df = x - scand[k][c];
      d[k] = fmaf(df, df, d[k]);
    }
  }

  float m = 3.4e38f;
#pragma unroll
  for (int k = 0; k < 9; ++k) {
    int rr = sr + k / 3 - 1, cc = sc + k % 3 - 1;
    bool valid = (rr >= 0 && rr < KNSH && cc >= 0 && cc < KNSW);
    if (valid) m = fminf(m, d[k]);
  }
  float e[9];
  float sum = 0.f;
#pragma unroll
  for (int k = 0; k < 9; ++k) {
    int rr = sr + k / 3 - 1, cc = sc + k % 3 - 1;
    bool valid = (rr >= 0 && rr < KNSH && cc >= 0 && cc < KNSW);
    e[k] = valid ? __expf(m - d[k]) : 0.f;
    sum += e[k];
  }
  float inv = 1.0f / sum;
#pragma unroll
  for (int k = 0; k < 9; ++k)
    aff[((size_t)b * 9 + k) * KN + p] = e[k] * inv;
}

// ---------------------------------------------------------------------------
// Kernel D: dense output writer (zero-or-value in one pass), NT stores.
// d_out accepts writes at only ~3 TB/s regardless of method (measured across
// R3-R8: memset/NT/plain all ~105-118 us on 327.7 MB; harness fill on d_out
// runs 1.7 TB/s vs 6.9 TB/s on d_ws) -> this stage is a harness-buffer floor.
__global__ __launch_bounds__(256) void write_out_kernel(
    const float* __restrict__ aff, float* __restrict__ out) {
  int wg = blockIdx.x;
  int s  = wg % KNS;
  int b  = wg / KNS;
  int sr = s / KNSW, sc = s % KNSW;
  int t  = threadIdx.x;

  float4v* orow = (float4v*)(out + ((size_t)b * KNS + s) * KN);
  const float* affb = aff + (size_t)b * 9 * KN;

  int it0 = blockIdx.y * 25;
#pragma unroll 5
  for (int ii = 0; ii < 25; ++ii) {
    int q = (it0 + ii) * 256 + t;  // float4 index in row
    int p = q * 4;
    unsigned r   = (unsigned)p / KW;
    unsigned col = (unsigned)p - r * KW;
    int r0 = (int)(r >> 4), c0 = (int)(col >> 4);
    int dr = sr - r0, dc = sc - c0;
    float4v v = (float4v)(0.f);
    if (dr >= -1 && dr <= 1 && dc >= -1 && dc <= 1) {
      int k = (dr + 1) * 3 + (dc + 1);
      v = *(const float4v*)(affb + (size_t)k * KN + p);
    }
    __builtin_nontemporal_store(v, &orow[q]);
  }
}

// ---------------------------------------------------------------------------
extern "C" void kernel_launch(void* const* d_in, const int* in_sizes, int n_in,
                              void* d_out, int out_size, void* d_ws, size_t ws_size,
                              hipStream_t stream) {
  const float* pf = (const float*)d_in[0];
  float* out = (float*)d_out;

  // ws (floats): spix0 [51200] | aff [1843200] | part [460800] | den [7200]
  float* spix0 = (float*)d_ws;
  float* affws = spix0 + (size_t)KB * KC * KNS;
  float* partw = affws + (size_t)KB * 9 * KN;
  float* denw  = partw + (size_t)KB * KNS * 9 * 64;

  block_mean_kernel<<<KB * KC * KNSH, 320, 0, stream>>>(pf, spix0);
  dist_partial_kernel<<<KB * KNS, 256, 0, stream>>>(pf, spix0, partw, denw);
  dist_aff2_kernel<<<KB * KNS, 256, 0, stream>>>(pf, partw, denw, affws);
  dim3 gridD(KB * KNS, 4);
  write_out_kernel<<<gridD, 256, 0, stream>>>(affws, out);
}

// Round 11
// 135.973 us; speedup vs baseline: 1.2004x; 1.2004x over previous
//
#include <hip/hip_runtime.h>

// Problem constants (fixed by setup_inputs: (2, 64, 320, 320), stoken 16x16)
#define KB   2
#define KC   64
#define KH   320
#define KW   320
#define KSH  16
#define KSW  16
#define KNSH 20
#define KNSW 20
#define KNS  400           // KNSH*KNSW
#define KN   102400        // KH*KW

// output float4 partition for fused zeroing
#define TOTF4  20480000L   // KB*KNS*KN/4
#define HALF4  10240000L
#define NCOMP  800         // compute wgs in BS / B'
#define NZWG   1248        // zero wgs appended (total 2048 ~ device wg capacity)

typedef float float4v __attribute__((ext_vector_type(4)));

// Zero-duty branch shared by BS and B': wgs [NCOMP, NCOMP+NZWG) write a
// contiguous half of d_out with NT zero stores, concurrently with the
// compute wgs (co-resident; different buffer than pf reads).
__device__ __forceinline__ bool zero_duty(float* out, long zstart, long zend) {
  if (blockIdx.x < NCOMP) return false;
  long tid = (long)(blockIdx.x - NCOMP) * 256 + threadIdx.x;
  const long stride = (long)NZWG * 256;
  float4v z = (float4v)(0.f);
  float4v* o = (float4v*)out;
  for (long i = zstart + tid; i < zend; i += stride)
    __builtin_nontemporal_store(z, &o[i]);
  return true;
}

// ---------------------------------------------------------------------------
// Kernel A: spix0 = per-block mean of pixel features.
__global__ __launch_bounds__(320) void block_mean_kernel(
    const float* __restrict__ pf, float* __restrict__ spix) {
  int wg = blockIdx.x;
  int rb = wg % KNSH;
  int c  = (wg / KNSH) % KC;
  int b  = wg / (KNSH * KC);
  int t  = threadIdx.x;  // 0..319

  const float* row0 = pf + ((size_t)(b * KC + c) * KH + rb * KSH) * KW;
  float acc = 0.f;
#pragma unroll
  for (int i = 0; i < KSH; ++i) acc += row0[i * KW + t];

#pragma unroll
  for (int off = 8; off > 0; off >>= 1) acc += __shfl_down(acc, off, 16);

  if ((t & 15) == 0)
    spix[(b * KC + c) * KNS + rb * KNSW + (t >> 4)] = acc * (1.0f / (KSH * KSW));
}

// ---------------------------------------------------------------------------
// Kernel BS: FUSED iter-0 dist/softmax + scatter-partials (R8-proven) +
// zero-duty wgs covering d_out[0, HALF4).
__global__ __launch_bounds__(256) void dist_partial_kernel(
    const float* __restrict__ pf, const float* __restrict__ spix,
    float* __restrict__ part, float* __restrict__ den,
    float* __restrict__ outz) {
  if (zero_duty(outz, 0L, HALF4)) return;

  __shared__ float scand[9][KC];
  __shared__ __align__(16) float aff_s[9][256];
  __shared__ float part_s[9][64];
  __shared__ float den_s[9];

  int wg = blockIdx.x;
  int s  = wg % KNS;
  int b  = wg / KNS;
  int sr = s / KNSW, sc = s % KNSW;
  int t  = threadIdx.x;

  // stage the 9 candidate centroids
  for (int idx = t; idx < 9 * KC; idx += 256) {
    int k = idx >> 6, c = idx & 63;
    int rr = sr + k / 3 - 1, cc = sc + k % 3 - 1;
    float v = 0.f;
    if (rr >= 0 && rr < KNSH && cc >= 0 && cc < KNSW)
      v = spix[(b * KC + c) * KNS + rr * KNSW + cc];
    scand[k][c] = v;
  }
  __syncthreads();

  // --- B phase: per-pixel distances + masked softmax (thread t = pixel t) ---
  int ti = t >> 4, tj = t & 15;
  int p = (sr * KSH + ti) * KW + sc * KSW + tj;
  const float* pfp = pf + (size_t)b * KC * KN + p;

  float d[9];
#pragma unroll
  for (int k = 0; k < 9; ++k) d[k] = 0.f;
  for (int c = 0; c < KC; ++c) {
    float x = pfp[(size_t)c * KN];
#pragma unroll
    for (int k = 0; k < 9; ++k) {
      float df = x - scand[k][c];
      d[k] = fmaf(df, df, d[k]);
    }
  }
  float m = 3.4e38f;
#pragma unroll
  for (int k = 0; k < 9; ++k) {
    int rr = sr + k / 3 - 1, cc = sc + k % 3 - 1;
    if (rr >= 0 && rr < KNSH && cc >= 0 && cc < KNSW) m = fminf(m, d[k]);
  }
  float e[9];
  float sum = 0.f;
#pragma unroll
  for (int k = 0; k < 9; ++k) {
    int rr = sr + k / 3 - 1, cc = sc + k % 3 - 1;
    bool valid = (rr >= 0 && rr < KNSH && cc >= 0 && cc < KNSW);
    e[k] = valid ? __expf(m - d[k]) : 0.f;
    sum += e[k];
  }
  float inv = 1.0f / sum;
#pragma unroll
  for (int k = 0; k < 9; ++k) aff_s[k][t] = e[k] * inv;
  __syncthreads();

  // --- S1 phase: scatter partials ---
  int w = t >> 6, l = t & 63;
  int li = l >> 2, lj4 = (l & 3) * 4;
  const float* pfb = pf + ((size_t)b * KC + w * 16) * KN
                   + (sr * KSH + li) * KW + sc * KSW + lj4;

  const float4v a0 = *(const float4v*)(&aff_s[0][l * 4]);
  const float4v a1 = *(const float4v*)(&aff_s[1][l * 4]);
  const float4v a2 = *(const float4v*)(&aff_s[2][l * 4]);
  const float4v a3 = *(const float4v*)(&aff_s[3][l * 4]);
  const float4v a4 = *(const float4v*)(&aff_s[4][l * 4]);
  const float4v a5 = *(const float4v*)(&aff_s[5][l * 4]);
  const float4v a6 = *(const float4v*)(&aff_s[6][l * 4]);
  const float4v a7 = *(const float4v*)(&aff_s[7][l * 4]);
  const float4v a8 = *(const float4v*)(&aff_s[8][l * 4]);

  if (w == 0) {
#define DENK(k, av)                                                       \
    {                                                                     \
      float dv = (av.x + av.y) + (av.z + av.w);                           \
      _Pragma("unroll")                                                   \
      for (int off = 32; off > 0; off >>= 1) dv += __shfl_xor(dv, off, 64); \
      if (l == 0) den_s[k] = dv;                                          \
    }
    DENK(0, a0) DENK(1, a1) DENK(2, a2) DENK(3, a3) DENK(4, a4)
    DENK(5, a5) DENK(6, a6) DENK(7, a7) DENK(8, a8)
#undef DENK
  }

#pragma unroll
  for (int cb = 0; cb < 4; ++cb) {
    float4v x0 = *(const float4v*)(pfb + (size_t)(cb * 4 + 0) * KN);
    float4v x1 = *(const float4v*)(pfb + (size_t)(cb * 4 + 1) * KN);
    float4v x2 = *(const float4v*)(pfb + (size_t)(cb * 4 + 2) * KN);
    float4v x3 = *(const float4v*)(pfb + (size_t)(cb * 4 + 3) * KN);

    float acc[4][9];
#define DOTS(c, xv)                                                        \
    acc[c][0] = fmaf(xv.x, a0.x, fmaf(xv.y, a0.y, fmaf(xv.z, a0.z, xv.w * a0.w))); \
    acc[c][1] = fmaf(xv.x, a1.x, fmaf(xv.y, a1.y, fmaf(xv.z, a1.z, xv.w * a1.w))); \
    acc[c][2] = fmaf(xv.x, a2.x, fmaf(xv.y, a2.y, fmaf(xv.z, a2.z, xv.w * a2.w))); \
    acc[c][3] = fmaf(xv.x, a3.x, fmaf(xv.y, a3.y, fmaf(xv.z, a3.z, xv.w * a3.w))); \
    acc[c][4] = fmaf(xv.x, a4.x, fmaf(xv.y, a4.y, fmaf(xv.z, a4.z, xv.w * a4.w))); \
    acc[c][5] = fmaf(xv.x, a5.x, fmaf(xv.y, a5.y, fmaf(xv.z, a5.z, xv.w * a5.w))); \
    acc[c][6] = fmaf(xv.x, a6.x, fmaf(xv.y, a6.y, fmaf(xv.z, a6.z, xv.w * a6.w))); \
    acc[c][7] = fmaf(xv.x, a7.x, fmaf(xv.y, a7.y, fmaf(xv.z, a7.z, xv.w * a7.w))); \
    acc[c][8] = fmaf(xv.x, a8.x, fmaf(xv.y, a8.y, fmaf(xv.z, a8.z, xv.w * a8.w)));
    DOTS(0, x0) DOTS(1, x1) DOTS(2, x2) DOTS(3, x3)
#undef DOTS

#pragma unroll
    for (int off = 32; off > 0; off >>= 1)
#pragma unroll
      for (int c = 0; c < 4; ++c)
#pragma unroll
        for (int k = 0; k < 9; ++k)
          acc[c][k] += __shfl_xor(acc[c][k], off, 64);

    if (l == 0) {
#pragma unroll
      for (int c = 0; c < 4; ++c)
#pragma unroll
        for (int k = 0; k < 9; ++k)
          part_s[k][w * 16 + cb * 4 + c] = acc[c][k];
    }
  }
  __syncthreads();

  size_t base = ((size_t)b * KNS + s) * 9;
  for (int idx = t; idx < 9 * 64; idx += 256)
    part[base * 64 + idx] = part_s[idx >> 6][idx & 63];
  if (t < 9) den[base + t] = den_s[t];
}

// ---------------------------------------------------------------------------
// Kernel B': iter-1 dist/softmax with S2 inlined + zero-duty wgs covering
// d_out[HALF4, TOTF4).
__global__ __launch_bounds__(256) void dist_aff2_kernel(
    const float* __restrict__ pf, const float* __restrict__ part,
    const float* __restrict__ den, float* __restrict__ aff,
    float* __restrict__ outz) {
  if (zero_duty(outz, HALF4, TOTF4)) return;

  __shared__ float scand[9][KC];

  int wg = blockIdx.x;
  int s  = wg % KNS;
  int b  = wg / KNS;
  int sr = s / KNSW, sc = s % KNSW;
  int t  = threadIdx.x;

  // scand[k][c] = spix1 of neighbor k, from the 9 partials around it
  for (int idx = t; idx < 9 * KC; idx += 256) {
    int k = idx >> 6, c = idx & 63;   // k uniform per 64-thread group
    int nr = sr + k / 3 - 1, nc = sc + k % 3 - 1;
    float v = 0.f;
    if (nr >= 0 && nr < KNSH && nc >= 0 && nc < KNSW) {
      float num = 0.f, dsum = 0.f;
#pragma unroll
      for (int j = 0; j < 9; ++j) {
        int rr = nr + j / 3 - 1, cc = nc + j % 3 - 1;
        if (rr >= 0 && rr < KNSH && cc >= 0 && cc < KNSW) {
          size_t base = ((size_t)b * KNS + rr * KNSW + cc) * 9 + (8 - j);
          num  += part[base * 64 + c];
          dsum += den[base];
        }
      }
      v = num / (dsum + 1e-16f);
    }
    scand[k][c] = v;
  }
  __syncthreads();

  int i = t >> 4, j = t & 15;
  int p = (sr * KSH + i) * KW + sc * KSW + j;
  const float* pfb = pf + (size_t)b * KC * KN + p;

  float d[9];
#pragma unroll
  for (int k = 0; k < 9; ++k) d[k] = 0.f;

  for (int c = 0; c < KC; ++c) {
    float x = pfb[(size_t)c * KN];
#pragma unroll
    for (int k = 0; k < 9; ++k) {
      float df = x - scand[k][c];
      d[k] = fmaf(df, df, d[k]);
    }
  }

  float m = 3.4e38f;
#pragma unroll
  for (int k = 0; k < 9; ++k) {
    int rr = sr + k / 3 - 1, cc = sc + k % 3 - 1;
    bool valid = (rr >= 0 && rr < KNSH && cc >= 0 && cc < KNSW);
    if (valid) m = fminf(m, d[k]);
  }
  float e[9];
  float sum = 0.f;
#pragma unroll
  for (int k = 0; k < 9; ++k) {
    int rr = sr + k / 3 - 1, cc = sc + k % 3 - 1;
    bool valid = (rr >= 0 && rr < KNSH && cc >= 0 && cc < KNSW);
    e[k] = valid ? __expf(m - d[k]) : 0.f;
    sum += e[k];
  }
  float inv = 1.0f / sum;
#pragma unroll
  for (int k = 0; k < 9; ++k)
    aff[((size_t)b * 9 + k) * KN + p] = e[k] * inv;
}

// ---------------------------------------------------------------------------
// Kernel D2: sparse valid-region writer (R6-proven). Writes only the <=48x48
// valid rect per output row (7.4 MB total), NT; zeros already laid down by
// the zero-duty wgs of BS and B'.
__global__ __launch_bounds__(256) void sparse_out_kernel(
    const float* __restrict__ aff, float* __restrict__ out) {
  int wg = blockIdx.x;
  int s  = wg % KNS;
  int b  = wg / KNS;
  int sr = s / KNSW, sc = s % KNSW;
  int t  = threadIdx.x;

  float* orow = out + ((size_t)b * KNS + s) * KN;
  const float* affb = aff + (size_t)b * 9 * KN;

  int rbase  = (sr - 1) * KSH;   // virtual 48-row x 12-float4 rect anchor
  int c4base = (sc - 1) * 4;

#pragma unroll
  for (int ii = 0; ii < 3; ++ii) {
    int idx = ii * 256 + t;      // 0..575 (48*12)
    if (idx >= 576) break;
    int vr = idx / 12, vc = idx - vr * 12;
    int r  = rbase + vr;
    int c4 = c4base + vc;
    if (r < 0 || r >= KH || c4 < 0 || c4 >= KW / 4) continue;
    // plane k s.t. pixel's candidate k == s:  k = 8 - 3*(vr/16) - (vc/4)
    int k = 8 - (vr >> 4) * 3 - (vc >> 2);
    int p = r * KW + c4 * 4;
    float4v v = *(const float4v*)(affb + (size_t)k * KN + p);
    __builtin_nontemporal_store(v, (float4v*)(orow + p));
  }
}

// ---------------------------------------------------------------------------
extern "C" void kernel_launch(void* const* d_in, const int* in_sizes, int n_in,
                              void* d_out, int out_size, void* d_ws, size_t ws_size,
                              hipStream_t stream) {
  const float* pf = (const float*)d_in[0];
  float* out = (float*)d_out;

  // ws (floats): spix0 [51200] | aff [1843200] | part [460800] | den [7200]
  float* spix0 = (float*)d_ws;
  float* affws = spix0 + (size_t)KB * KC * KNS;
  float* partw = affws + (size_t)KB * 9 * KN;
  float* denw  = partw + (size_t)KB * KNS * 9 * 64;

  block_mean_kernel<<<KB * KC * KNSH, 320, 0, stream>>>(pf, spix0);
  dist_partial_kernel<<<NCOMP + NZWG, 256, 0, stream>>>(pf, spix0, partw, denw, out);
  dist_aff2_kernel<<<NCOMP + NZWG, 256, 0, stream>>>(pf, partw, denw, affws, out);
  sparse_out_kernel<<<KB * KNS, 256, 0, stream>>>(affws, out);
}